// Round 22
// baseline (315.734 us; speedup 1.0000x reference)
//
#include <hip/hip_runtime.h>

typedef __bf16 bf16x8 __attribute__((ext_vector_type(8)));
typedef __bf16 bf16x4 __attribute__((ext_vector_type(4)));
typedef float f32x4 __attribute__((ext_vector_type(4)));

__device__ __forceinline__ void gl_lds16(const void* g, void* l) {
  __builtin_amdgcn_global_load_lds(
      (const __attribute__((address_space(1))) unsigned int*)g,
      (__attribute__((address_space(3))) unsigned int*)l, 16, 0, 0);
}

// ---------------- f32 -> bf16 convert (vectorized, native casts) ----------------
__global__ __launch_bounds__(256) void conv_bf16_kernel(
    const float* __restrict__ in, __bf16* __restrict__ out, int n4) {
  int i = blockIdx.x * 256 + threadIdx.x;
  if (i < n4) {
    float4 v = ((const float4*)in)[i];
    bf16x4 o;
    o[0] = (__bf16)v.x; o[1] = (__bf16)v.y; o[2] = (__bf16)v.z; o[3] = (__bf16)v.w;
    *(bf16x4*)(out + (size_t)i * 4) = o;
  }
}

// ---------------- f32 [R][C] -> bf16 transposed [C][R] ----------------
__global__ __launch_bounds__(256) void tconv_kernel(
    const float* __restrict__ W, __bf16* __restrict__ Wt, int R, int C) {
  __shared__ float t[32][33];
  int c0 = blockIdx.x * 32, r0 = blockIdx.y * 32;
  int tx = threadIdx.x, ty = threadIdx.y;
#pragma unroll
  for (int i = 0; i < 4; ++i)
    t[ty + i * 8][tx] = W[(size_t)(r0 + ty + i * 8) * C + c0 + tx];
  __syncthreads();
#pragma unroll
  for (int i = 0; i < 4; ++i)
    Wt[(size_t)(c0 + ty + i * 8) * R + r0 + tx] = (__bf16)t[tx][ty + i * 8];
}

// ---------------- bf16 GEMM (2-phase dbuf, gl_lds A+B): C[M,N] = A[M,K] * Bt[N,K]^T ----
// NORM==1: per-64-col RMSNorm (q) with the softmax scale C=log2(e)/8 folded in.
// NORM==2: KV mode (K compact + V transp-permute). NORM==0: plain; OUTF32 -> f32 out.
template <int NORM, int OUTF32>
__global__ __launch_bounds__(256) void gemm_kernel(
    const __bf16* __restrict__ Ab, const __bf16* __restrict__ Bt,
    void* __restrict__ Cout, void* __restrict__ Cout2,
    int M, int N, int K, const float* __restrict__ gamma) {
  __shared__ alignas(16) __bf16 Alds[2][128 * 32];
  __shared__ alignas(16) __bf16 Blds[2][128 * 32];
  const int tid = threadIdx.x;
  const int w = tid >> 6, l = tid & 63;
  const int lg = l & 15, lh = l >> 4;
  const int wr = w >> 1, wc = w & 1;

  // XCD-bijective swizzle: same-XCD blocks walk bcol fastest within a brow-slab.
  const int nbx = gridDim.x;
  const int lid = blockIdx.y * nbx + blockIdx.x;
  const int cpx = (nbx * gridDim.y) >> 3;
  const int swz = (lid & 7) * cpx + (lid >> 3);
  const int brow = (swz / nbx) * 128, bcol = (swz % nbx) * 128;

  const f32x4 zero = {0.f, 0.f, 0.f, 0.f};
  f32x4 acc[4][4];
#pragma unroll
  for (int m = 0; m < 4; ++m)
#pragma unroll
    for (int n = 0; n < 4; ++n) acc[m][n] = zero;

  auto STAGE = [&](int buf, int k0) {
#pragma unroll
    for (int j = 0; j < 2; ++j) {
      int c = j * 256 + w * 64 + l;
      gl_lds16(Ab + (size_t)(brow + (c >> 2)) * K + k0 + (c & 3) * 8,
               (char*)Alds[buf] + (j * 256 + w * 64) * 16);
      gl_lds16(Bt + (size_t)(bcol + (c >> 2)) * K + k0 + (c & 3) * 8,
               (char*)Blds[buf] + (j * 256 + w * 64) * 16);
    }
  };

  STAGE(0, 0);
  __syncthreads();
  for (int k0 = 0; k0 < K; k0 += 32) {
    int cur = (k0 >> 5) & 1;
    if (k0 + 32 < K) STAGE(cur ^ 1, k0 + 32);
    bf16x8 af[4], bfr[4];
#pragma unroll
    for (int m = 0; m < 4; ++m)
      af[m] = *(const bf16x8*)(Alds[cur] + (wr * 64 + m * 16 + lg) * 32 + lh * 8);
#pragma unroll
    for (int n = 0; n < 4; ++n)
      bfr[n] = *(const bf16x8*)(Blds[cur] + (wc * 64 + n * 16 + lg) * 32 + lh * 8);
#pragma unroll
    for (int m = 0; m < 4; ++m)
#pragma unroll
      for (int n = 0; n < 4; ++n)
        acc[m][n] = __builtin_amdgcn_mfma_f32_16x16x32_bf16(af[m], bfr[n], acc[m][n], 0, 0, 0);
    __syncthreads();
  }

  const int col64 = bcol + wc * 64;
  if (NORM == 1 || (NORM == 2 && col64 < 1024)) {
    const float QS = (NORM == 1) ? 0.18033688f : 1.0f;  // fold log2(e)/8 into Q
    float gm[4];
#pragma unroll
    for (int n = 0; n < 4; ++n) gm[n] = gamma[n * 16 + lg] * QS;
#pragma unroll
    for (int m = 0; m < 4; ++m) {
#pragma unroll
      for (int i = 0; i < 4; ++i) {
        float ss = 0.f;
#pragma unroll
        for (int n = 0; n < 4; ++n) ss += acc[m][n][i] * acc[m][n][i];
        ss += __shfl_xor(ss, 1);
        ss += __shfl_xor(ss, 2);
        ss += __shfl_xor(ss, 4);
        ss += __shfl_xor(ss, 8);
        float inv = rsqrtf(ss * (1.0f / 64.0f) + 1e-6f);
#pragma unroll
        for (int n = 0; n < 4; ++n) acc[m][n][i] *= inv * gm[n];
      }
    }
  }

  if (NORM == 2) {
    if (col64 < 1024) {
#pragma unroll
      for (int m = 0; m < 4; ++m)
#pragma unroll
        for (int n = 0; n < 4; ++n)
#pragma unroll
          for (int i = 0; i < 4; ++i) {
            size_t idx = (size_t)(brow + wr * 64 + m * 16 + lh * 4 + i) * 1024 +
                         col64 + n * 16 + lg;
            ((__bf16*)Cout)[idx] = (__bf16)acc[m][n][i];
          }
    } else {
      // V half -> Vt[b,h,d,kvp]: i-dim = 4 consecutive kv = contiguous after permute
#pragma unroll
      for (int m = 0; m < 4; ++m) {
        int row = brow + wr * 64 + m * 16 + lh * 4;   // global ctx row = b*1024 + kv
        int bb = row >> 10, kv0 = row & 1023;
        int g = kv0 & 31;
        int pos = (kv0 & ~31) + ((g & 15) >> 2) * 8 + (g >> 4) * 4;
#pragma unroll
        for (int n = 0; n < 4; ++n) {
          int col = col64 + n * 16 + lg - 1024;       // = h*64 + d
          bf16x4 v;
#pragma unroll
          for (int i = 0; i < 4; ++i) v[i] = (__bf16)acc[m][n][i];
          *(bf16x4*)((__bf16*)Cout2 + ((size_t)(bb * 1024 + col)) * 1024 + pos) = v;
        }
      }
    }
    return;
  }

#pragma unroll
  for (int m = 0; m < 4; ++m)
#pragma unroll
    for (int n = 0; n < 4; ++n)
#pragma unroll
      for (int i = 0; i < 4; ++i) {
        size_t idx = (size_t)(brow + wr * 64 + m * 16 + lh * 4 + i) * N +
                     bcol + wc * 64 + n * 16 + lg;
        if (OUTF32) ((float*)Cout)[idx] = acc[m][n][i];
        else ((__bf16*)Cout)[idx] = (__bf16)acc[m][n][i];
      }
}

// ---------------- flash attention v15: 64 q/wave, 256-thr blocks, VGPR cap 256 --------
// Q pre-scaled by C=log2(e)/8; P = exp2(st); shift cancels in O = sum(PV)/sum(P).
// 4 waves/block: __launch_bounds__(256, 2) -> min 2 waves/EU -> per-wave VGPR cap 256,
// which fits the ~220-reg working set WITHOUT spilling (512-thr blocks forced a 128 cap
// in rounds 20/21 -> 255 MB scratch). 2 blocks/CU = 8 waves/CU, LDS 2x64KB = 128KB.
__global__ __launch_bounds__(256, 2) void flash_kernel(
    const __bf16* __restrict__ Qb, const __bf16* __restrict__ Kb,
    const __bf16* __restrict__ Vt, __bf16* __restrict__ Ob) {
  // XCD-aware bijective swizzle: 1024 blocks, 8 XCDs, 128 per XCD.
  const int orig = blockIdx.x;
  const int wgid = (orig & 7) * 128 + (orig >> 3);
  const int qt = wgid & 15, h = (wgid >> 4) & 15, b = wgid >> 8;
  const int tid = threadIdx.x;
  const int w = tid >> 6, l = tid & 63, lg = l & 15, lh = l >> 4;
  // K buf n at n*8192 ; V buf n at 32768 + n*8192  (n = 0..3)
  __shared__ alignas(16) char lds[65536];

  const int qrow0 = b * 4096 + qt * 256 + w * 64;
  bf16x8 qfr[4][2];
#pragma unroll
  for (int mff = 0; mff < 4; ++mff)
#pragma unroll
    for (int dc = 0; dc < 2; ++dc)
      qfr[mff][dc] = *(const bf16x8*)(Qb + (size_t)(qrow0 + mff * 16 + lg) * 1024 +
                                      h * 64 + dc * 32 + lh * 8);

  const char* Kg = (const char*)Kb + (size_t)b * 2097152 + h * 128;  // row stride 2048B
  const char* Vg = (const char*)Vt + (size_t)(b * 16 + h) * 64 * 2048;

  // staging: 2 passes x (1 K-load + 1 V-load) per thread; linear LDS dest,
  // pre-swizzled global source (per-pass offsets are compile-time hoisted)
  auto STAGE = [&](int buf, int kt) {
#pragma unroll
    for (int j = 0; j < 2; ++j) {
      int o16 = (j * 256 + w * 64 + l) * 16;
      int op = o16 ^ (((o16 >> 7) & 7) << 4);
      int row = op >> 7, cb = op & 127;
      gl_lds16(Kg + (size_t)(kt * 64 + row) * 2048 + cb,
               lds + buf * 8192 + (j * 256 + w * 64) * 16);
      gl_lds16(Vg + (size_t)row * 2048 + kt * 128 + cb,
               lds + 32768 + buf * 8192 + (j * 256 + w * 64) * 16);
    }
  };

  // hoisted lane-invariant LDS read offsets
  const int swzl = (lg & 7) << 4;
  const int off0 = lg * 128 + ((lh * 16) ^ swzl);
  const int off1 = lg * 128 + ((64 + lh * 16) ^ swzl);

  const f32x4 zero = {0.f, 0.f, 0.f, 0.f};
  f32x4 o_[4][4];   // [df][qf] : O^T frag, row d = df*16+lh*4+i, col q = qf*16+lg
  float lp_[4];
#pragma unroll
  for (int df = 0; df < 4; ++df)
#pragma unroll
    for (int qf = 0; qf < 4; ++qf) o_[df][qf] = zero;
#pragma unroll
  for (int qf = 0; qf < 4; ++qf) lp_[qf] = 0.f;

  auto COMPUTE = [&](const char* Kc, const char* Vc) {
    // S^T[kv][q] : A = K rows (kv), B = Q cols (q); first K-slice uses zero C
    f32x4 st[4][4];
    __builtin_amdgcn_s_setprio(1);
#pragma unroll
    for (int kvf = 0; kvf < 4; ++kvf) {
      bf16x8 kf = *(const bf16x8*)(Kc + off0 + kvf * 2048);
#pragma unroll
      for (int mff = 0; mff < 4; ++mff)
        st[kvf][mff] = __builtin_amdgcn_mfma_f32_16x16x32_bf16(kf, qfr[mff][0], zero, 0, 0, 0);
    }
#pragma unroll
    for (int kvf = 0; kvf < 4; ++kvf) {
      bf16x8 kf = *(const bf16x8*)(Kc + off1 + kvf * 2048);
#pragma unroll
      for (int mff = 0; mff < 4; ++mff)
        st[kvf][mff] = __builtin_amdgcn_mfma_f32_16x16x32_bf16(kf, qfr[mff][1], st[kvf][mff], 0, 0, 0);
    }
    __builtin_amdgcn_s_setprio(0);

    // P = exp2(st), per-lane partial row-sum, direct pack into PV B-fragments
    bf16x8 pw[2][4];
#pragma unroll
    for (int qf = 0; qf < 4; ++qf) {
      float rs = 0.f;
#pragma unroll
      for (int kvf = 0; kvf < 4; ++kvf) {
#pragma unroll
        for (int i = 0; i < 4; ++i) {
          float p = __builtin_amdgcn_exp2f(st[kvf][qf][i]);
          pw[kvf >> 1][qf][(kvf & 1) * 4 + i] = (__bf16)p;
          rs += p;
        }
      }
      lp_[qf] += rs;   // cross-lane reduce deferred to epilogue
    }

    // O^T += V^T P : K32 MFMA; each b128 V read feeds 4 q-fragments
    __builtin_amdgcn_s_setprio(1);
#pragma unroll
    for (int p = 0; p < 2; ++p)
#pragma unroll
      for (int df = 0; df < 4; ++df) {
        bf16x8 vv = *(const bf16x8*)(Vc + (p ? off1 : off0) + df * 2048);
#pragma unroll
        for (int qf = 0; qf < 4; ++qf)
          o_[df][qf] = __builtin_amdgcn_mfma_f32_16x16x32_bf16(vv, pw[p][qf], o_[df][qf], 0, 0, 0);
      }
    __builtin_amdgcn_s_setprio(0);
  };

  STAGE(0, 0);
  STAGE(1, 1);
  __syncthreads();
#pragma unroll 2
  for (int it = 0; it < 8; ++it) {
    const int pb_ = (it & 1) * 2;           // current buffer pair {pb_, pb_+1}
    if (it < 7) {                           // prefetch next pair (read-done via prev barrier)
      STAGE(pb_ ^ 2, 2 * it + 2);
      STAGE((pb_ ^ 2) + 1, 2 * it + 3);
    }
    COMPUTE(lds + pb_ * 8192, lds + 32768 + pb_ * 8192);
    COMPUTE(lds + (pb_ + 1) * 8192, lds + 32768 + (pb_ + 1) * 8192);
    // drain this iteration's prefetch before the single barrier per 2 tiles
    asm volatile("s_waitcnt vmcnt(0)" ::: "memory");
    __syncthreads();
  }

  // final l reduce + normalize + store (i-dim = consecutive d -> 8B stores)
#pragma unroll
  for (int qf = 0; qf < 4; ++qf) {
    float ls = lp_[qf];
    ls += __shfl_xor(ls, 16);
    ls += __shfl_xor(ls, 32);
    float inv = 1.f / ls;
    size_t qrow = (size_t)(qrow0 + qf * 16 + lg) * 1024 + h * 64;
#pragma unroll
    for (int df = 0; df < 4; ++df) {
      bf16x4 ov;
#pragma unroll
      for (int i = 0; i < 4; ++i) ov[i] = (__bf16)(o_[df][qf][i] * inv);
      *(bf16x4*)(Ob + qrow + df * 16 + lh * 4) = ov;
    }
  }
}

extern "C" void kernel_launch(void* const* d_in, const int* in_sizes, int n_in,
                              void* d_out, int out_size, void* d_ws, size_t ws_size,
                              hipStream_t stream) {
  const float* x     = (const float*)d_in[0];
  const float* ctx   = (const float*)d_in[1];
  const float* Wq    = (const float*)d_in[2];
  const float* Wkv   = (const float*)d_in[3];
  const float* Wproj = (const float*)d_in[4];
  const float* qg    = (const float*)d_in[5];
  const float* kg    = (const float*)d_in[6];
  float* out = (float*)d_out;

  // B=4 L=4096 Lc=1024 D=1024 CTX=1024 H=16 hd=64
  char* ws = (char*)d_ws;
  __bf16* xb   = (__bf16*)(ws);                        // 32MB [16384,1024]; reused as Ob
  __bf16* cb   = (__bf16*)(ws + (size_t)32 * 1048576); // 8MB  [4096,1024]
  __bf16* Wqt  = (__bf16*)(ws + (size_t)40 * 1048576); // 2MB
  __bf16* Wkvt = (__bf16*)(ws + (size_t)42 * 1048576); // 4MB
  __bf16* Wpt  = (__bf16*)(ws + (size_t)46 * 1048576); // 2MB
  __bf16* Qb   = (__bf16*)(ws + (size_t)48 * 1048576); // 32MB
  __bf16* Kb   = (__bf16*)(ws + (size_t)80 * 1048576); // 8MB  [4096,1024]
  __bf16* Vt   = (__bf16*)(ws + (size_t)88 * 1048576); // 8MB  [b,h,d,kvp]
  __bf16* Ob   = xb;  // xb is dead after the Q GEMM

  conv_bf16_kernel<<<16384, 256, 0, stream>>>(x, xb, 4194304);
  conv_bf16_kernel<<<4096, 256, 0, stream>>>(ctx, cb, 1048576);
  tconv_kernel<<<dim3(32, 32), dim3(32, 8), 0, stream>>>(Wq, Wqt, 1024, 1024);
  tconv_kernel<<<dim3(64, 32), dim3(32, 8), 0, stream>>>(Wkv, Wkvt, 1024, 2048);
  tconv_kernel<<<dim3(32, 32), dim3(32, 8), 0, stream>>>(Wproj, Wpt, 1024, 1024);

  // Q = xb Wq (+q RMSNorm fused, softmax scale folded), bf16 A via gl_lds
  gemm_kernel<1, 0><<<dim3(8, 128), 256, 0, stream>>>(xb, Wqt, Qb, nullptr, 16384, 1024, 1024, qg);
  // KV = cb Wkv (+k RMSNorm on K half; V transposed+permuted), bf16 A via gl_lds
  gemm_kernel<2, 0><<<dim3(16, 32), 256, 0, stream>>>(cb, Wkvt, Kb, Vt, 4096, 2048, 1024, kg);
  flash_kernel<<<1024, 256, 0, stream>>>(Qb, Kb, Vt, Ob);
  // out = O Wproj, f32 out
  gemm_kernel<0, 1><<<dim3(8, 128), 256, 0, stream>>>(Ob, Wpt, out, nullptr, 16384, 1024, 1024, nullptr);
}

// Round 23
// 240.907 us; speedup vs baseline: 1.3106x; 1.3106x over previous
//
#include <hip/hip_runtime.h>

typedef __bf16 bf16x8 __attribute__((ext_vector_type(8)));
typedef __bf16 bf16x4 __attribute__((ext_vector_type(4)));
typedef float f32x4 __attribute__((ext_vector_type(4)));

__device__ __forceinline__ void gl_lds16(const void* g, void* l) {
  __builtin_amdgcn_global_load_lds(
      (const __attribute__((address_space(1))) unsigned int*)g,
      (__attribute__((address_space(3))) unsigned int*)l, 16, 0, 0);
}

// ---------------- f32 -> bf16 convert (vectorized, native casts) ----------------
__global__ __launch_bounds__(256) void conv_bf16_kernel(
    const float* __restrict__ in, __bf16* __restrict__ out, int n4) {
  int i = blockIdx.x * 256 + threadIdx.x;
  if (i < n4) {
    float4 v = ((const float4*)in)[i];
    bf16x4 o;
    o[0] = (__bf16)v.x; o[1] = (__bf16)v.y; o[2] = (__bf16)v.z; o[3] = (__bf16)v.w;
    *(bf16x4*)(out + (size_t)i * 4) = o;
  }
}

// ---------------- f32 [R][C] -> bf16 transposed [C][R] ----------------
__global__ __launch_bounds__(256) void tconv_kernel(
    const float* __restrict__ W, __bf16* __restrict__ Wt, int R, int C) {
  __shared__ float t[32][33];
  int c0 = blockIdx.x * 32, r0 = blockIdx.y * 32;
  int tx = threadIdx.x, ty = threadIdx.y;
#pragma unroll
  for (int i = 0; i < 4; ++i)
    t[ty + i * 8][tx] = W[(size_t)(r0 + ty + i * 8) * C + c0 + tx];
  __syncthreads();
#pragma unroll
  for (int i = 0; i < 4; ++i)
    Wt[(size_t)(c0 + ty + i * 8) * R + r0 + tx] = (__bf16)t[tx][ty + i * 8];
}

// ---------------- bf16 GEMM (2-phase dbuf, gl_lds A+B): C[M,N] = A[M,K] * Bt[N,K]^T ----
// NORM==1: per-64-col RMSNorm (q) with the softmax scale C=log2(e)/8 folded in.
// NORM==2: KV mode (K compact + V transp-permute). NORM==0: plain; OUTF32 -> f32 out.
template <int NORM, int OUTF32>
__global__ __launch_bounds__(256) void gemm_kernel(
    const __bf16* __restrict__ Ab, const __bf16* __restrict__ Bt,
    void* __restrict__ Cout, void* __restrict__ Cout2,
    int M, int N, int K, const float* __restrict__ gamma) {
  __shared__ alignas(16) __bf16 Alds[2][128 * 32];
  __shared__ alignas(16) __bf16 Blds[2][128 * 32];
  const int tid = threadIdx.x;
  const int w = tid >> 6, l = tid & 63;
  const int lg = l & 15, lh = l >> 4;
  const int wr = w >> 1, wc = w & 1;

  // XCD-bijective swizzle: same-XCD blocks walk bcol fastest within a brow-slab.
  const int nbx = gridDim.x;
  const int lid = blockIdx.y * nbx + blockIdx.x;
  const int cpx = (nbx * gridDim.y) >> 3;
  const int swz = (lid & 7) * cpx + (lid >> 3);
  const int brow = (swz / nbx) * 128, bcol = (swz % nbx) * 128;

  const f32x4 zero = {0.f, 0.f, 0.f, 0.f};
  f32x4 acc[4][4];
#pragma unroll
  for (int m = 0; m < 4; ++m)
#pragma unroll
    for (int n = 0; n < 4; ++n) acc[m][n] = zero;

  auto STAGE = [&](int buf, int k0) {
#pragma unroll
    for (int j = 0; j < 2; ++j) {
      int c = j * 256 + w * 64 + l;
      gl_lds16(Ab + (size_t)(brow + (c >> 2)) * K + k0 + (c & 3) * 8,
               (char*)Alds[buf] + (j * 256 + w * 64) * 16);
      gl_lds16(Bt + (size_t)(bcol + (c >> 2)) * K + k0 + (c & 3) * 8,
               (char*)Blds[buf] + (j * 256 + w * 64) * 16);
    }
  };

  STAGE(0, 0);
  __syncthreads();
  for (int k0 = 0; k0 < K; k0 += 32) {
    int cur = (k0 >> 5) & 1;
    if (k0 + 32 < K) STAGE(cur ^ 1, k0 + 32);
    bf16x8 af[4], bfr[4];
#pragma unroll
    for (int m = 0; m < 4; ++m)
      af[m] = *(const bf16x8*)(Alds[cur] + (wr * 64 + m * 16 + lg) * 32 + lh * 8);
#pragma unroll
    for (int n = 0; n < 4; ++n)
      bfr[n] = *(const bf16x8*)(Blds[cur] + (wc * 64 + n * 16 + lg) * 32 + lh * 8);
#pragma unroll
    for (int m = 0; m < 4; ++m)
#pragma unroll
      for (int n = 0; n < 4; ++n)
        acc[m][n] = __builtin_amdgcn_mfma_f32_16x16x32_bf16(af[m], bfr[n], acc[m][n], 0, 0, 0);
    __syncthreads();
  }

  const int col64 = bcol + wc * 64;
  if (NORM == 1 || (NORM == 2 && col64 < 1024)) {
    const float QS = (NORM == 1) ? 0.18033688f : 1.0f;  // fold log2(e)/8 into Q
    float gm[4];
#pragma unroll
    for (int n = 0; n < 4; ++n) gm[n] = gamma[n * 16 + lg] * QS;
#pragma unroll
    for (int m = 0; m < 4; ++m) {
#pragma unroll
      for (int i = 0; i < 4; ++i) {
        float ss = 0.f;
#pragma unroll
        for (int n = 0; n < 4; ++n) ss += acc[m][n][i] * acc[m][n][i];
        ss += __shfl_xor(ss, 1);
        ss += __shfl_xor(ss, 2);
        ss += __shfl_xor(ss, 4);
        ss += __shfl_xor(ss, 8);
        float inv = rsqrtf(ss * (1.0f / 64.0f) + 1e-6f);
#pragma unroll
        for (int n = 0; n < 4; ++n) acc[m][n][i] *= inv * gm[n];
      }
    }
  }

  if (NORM == 2) {
    if (col64 < 1024) {
#pragma unroll
      for (int m = 0; m < 4; ++m)
#pragma unroll
        for (int n = 0; n < 4; ++n)
#pragma unroll
          for (int i = 0; i < 4; ++i) {
            size_t idx = (size_t)(brow + wr * 64 + m * 16 + lh * 4 + i) * 1024 +
                         col64 + n * 16 + lg;
            ((__bf16*)Cout)[idx] = (__bf16)acc[m][n][i];
          }
    } else {
      // V half -> Vt[b,h,d,kvp]: i-dim = 4 consecutive kv = contiguous after permute
#pragma unroll
      for (int m = 0; m < 4; ++m) {
        int row = brow + wr * 64 + m * 16 + lh * 4;   // global ctx row = b*1024 + kv
        int bb = row >> 10, kv0 = row & 1023;
        int g = kv0 & 31;
        int pos = (kv0 & ~31) + ((g & 15) >> 2) * 8 + (g >> 4) * 4;
#pragma unroll
        for (int n = 0; n < 4; ++n) {
          int col = col64 + n * 16 + lg - 1024;       // = h*64 + d
          bf16x4 v;
#pragma unroll
          for (int i = 0; i < 4; ++i) v[i] = (__bf16)acc[m][n][i];
          *(bf16x4*)((__bf16*)Cout2 + ((size_t)(bb * 1024 + col)) * 1024 + pos) = v;
        }
      }
    }
    return;
  }

#pragma unroll
  for (int m = 0; m < 4; ++m)
#pragma unroll
    for (int n = 0; n < 4; ++n)
#pragma unroll
      for (int i = 0; i < 4; ++i) {
        size_t idx = (size_t)(brow + wr * 64 + m * 16 + lh * 4 + i) * N +
                     bcol + wc * 64 + n * 16 + lg;
        if (OUTF32) ((float*)Cout)[idx] = acc[m][n][i];
        else ((__bf16*)Cout)[idx] = (__bf16)acc[m][n][i];
      }
}

// ---------------- flash attention v12: pre-scaled Q, shift-free softmax ----------------
// Q was pre-scaled by C=log2(e)/8 in the Q-GEMM epilogue, so st = S*C and
// P = exp2(st) directly. |st| <= 64*C = 11.54 -> P <= 2^11.54 ~ 2900 (f32/bf16 safe);
// the softmax shift cancels between numerator and denominator (O = sum(PV)/sum(P)).
__global__ __launch_bounds__(512) void flash_kernel(
    const __bf16* __restrict__ Qb, const __bf16* __restrict__ Kb,
    const __bf16* __restrict__ Vt, __bf16* __restrict__ Ob) {
  // XCD-aware bijective swizzle: 1024 blocks, 8 XCDs, 128 per XCD.
  const int orig = blockIdx.x;
  const int wgid = (orig & 7) * 128 + (orig >> 3);
  const int qt = wgid & 15, h = (wgid >> 4) & 15, b = wgid >> 8;
  const int tid = threadIdx.x;
  const int w = tid >> 6, l = tid & 63, lg = l & 15, lh = l >> 4;
  // K buf n at n*8192 ; V buf n at 32768 + n*8192  (n = 0..3)
  __shared__ alignas(16) char lds[65536];

  const int qrow0 = b * 4096 + qt * 256 + w * 32;
  bf16x8 qfr[2][2];
#pragma unroll
  for (int mff = 0; mff < 2; ++mff)
#pragma unroll
    for (int dc = 0; dc < 2; ++dc)
      qfr[mff][dc] = *(const bf16x8*)(Qb + (size_t)(qrow0 + mff * 16 + lg) * 1024 +
                                      h * 64 + dc * 32 + lh * 8);

  const char* Kg = (const char*)Kb + (size_t)b * 2097152 + h * 128;  // row stride 2048B
  const char* Vg = (const char*)Vt + (size_t)(b * 16 + h) * 64 * 2048;

  // staging: per-thread 1 K-load + 1 V-load per tile; linear LDS dest, pre-swizzled src
  const int o16 = tid * 16;
  const int op = o16 ^ (((o16 >> 7) & 7) << 4);
  const int srow = op >> 7, scb = op & 127;

  auto STAGE = [&](int buf, int kt) {
    gl_lds16(Kg + (size_t)(kt * 64 + srow) * 2048 + scb, lds + buf * 8192 + w * 1024);
    gl_lds16(Vg + (size_t)srow * 2048 + kt * 128 + scb, lds + 32768 + buf * 8192 + w * 1024);
  };

  // hoisted lane-invariant LDS read offsets
  const int swzl = (lg & 7) << 4;
  const int off0 = lg * 128 + ((lh * 16) ^ swzl);
  const int off1 = lg * 128 + ((64 + lh * 16) ^ swzl);

  const f32x4 zero = {0.f, 0.f, 0.f, 0.f};
  f32x4 o_[4][2];   // [df][qf] : O^T frag, row d = df*16+lh*4+i, col q = qf*16+lg
  float lp_[2];
#pragma unroll
  for (int df = 0; df < 4; ++df)
#pragma unroll
    for (int qf = 0; qf < 2; ++qf) o_[df][qf] = zero;
  lp_[0] = lp_[1] = 0.f;

  auto COMPUTE = [&](const char* Kc, const char* Vc) {
    // S^T[kv][q] : A = K rows (kv), B = Q cols (q); first K-slice uses zero C
    f32x4 st[4][2];
    __builtin_amdgcn_s_setprio(1);
#pragma unroll
    for (int kvf = 0; kvf < 4; ++kvf) {
      bf16x8 kf = *(const bf16x8*)(Kc + off0 + kvf * 2048);
#pragma unroll
      for (int mff = 0; mff < 2; ++mff)
        st[kvf][mff] = __builtin_amdgcn_mfma_f32_16x16x32_bf16(kf, qfr[mff][0], zero, 0, 0, 0);
    }
#pragma unroll
    for (int kvf = 0; kvf < 4; ++kvf) {
      bf16x8 kf = *(const bf16x8*)(Kc + off1 + kvf * 2048);
#pragma unroll
      for (int mff = 0; mff < 2; ++mff)
        st[kvf][mff] = __builtin_amdgcn_mfma_f32_16x16x32_bf16(kf, qfr[mff][1], st[kvf][mff], 0, 0, 0);
    }
    __builtin_amdgcn_s_setprio(0);

    // P = exp2(st) (Q pre-scaled; shift cancels), per-lane partial row-sum, direct pack
    bf16x8 pw[2][2];
#pragma unroll
    for (int qf = 0; qf < 2; ++qf) {
      float rs = 0.f;
#pragma unroll
      for (int kvf = 0; kvf < 4; ++kvf) {
#pragma unroll
        for (int i = 0; i < 4; ++i) {
          float p = __builtin_amdgcn_exp2f(st[kvf][qf][i]);
          pw[kvf >> 1][qf][(kvf & 1) * 4 + i] = (__bf16)p;
          rs += p;
        }
      }
      lp_[qf] += rs;   // cross-lane reduce deferred to epilogue
    }

    // O^T += V^T P : K32 MFMA; b128 V read = A-frag, pw = B-frag
    __builtin_amdgcn_s_setprio(1);
#pragma unroll
    for (int p = 0; p < 2; ++p)
#pragma unroll
      for (int df = 0; df < 4; ++df) {
        bf16x8 vv = *(const bf16x8*)(Vc + (p ? off1 : off0) + df * 2048);
#pragma unroll
        for (int qf = 0; qf < 2; ++qf)
          o_[df][qf] = __builtin_amdgcn_mfma_f32_16x16x32_bf16(vv, pw[p][qf], o_[df][qf], 0, 0, 0);
      }
    __builtin_amdgcn_s_setprio(0);
  };

  STAGE(0, 0);
  STAGE(1, 1);
  __syncthreads();
#pragma unroll 2
  for (int it = 0; it < 8; ++it) {
    const int pb_ = (it & 1) * 2;           // current buffer pair {pb_, pb_+1}
    if (it < 7) {                           // prefetch next pair (read-done via prev barrier)
      STAGE(pb_ ^ 2, 2 * it + 2);
      STAGE((pb_ ^ 2) + 1, 2 * it + 3);
    }
    COMPUTE(lds + pb_ * 8192, lds + 32768 + pb_ * 8192);
    COMPUTE(lds + (pb_ + 1) * 8192, lds + 32768 + (pb_ + 1) * 8192);
    // drain this iteration's prefetch before the single barrier per 2 tiles
    asm volatile("s_waitcnt vmcnt(0)" ::: "memory");
    __syncthreads();
  }

  // final l reduce + normalize + store (i-dim = consecutive d -> 8B stores)
#pragma unroll
  for (int qf = 0; qf < 2; ++qf) {
    float ls = lp_[qf];
    ls += __shfl_xor(ls, 16);
    ls += __shfl_xor(ls, 32);
    float inv = 1.f / ls;
    size_t qrow = (size_t)(qrow0 + qf * 16 + lg) * 1024 + h * 64;
#pragma unroll
    for (int df = 0; df < 4; ++df) {
      bf16x4 ov;
#pragma unroll
      for (int i = 0; i < 4; ++i) ov[i] = (__bf16)(o_[df][qf][i] * inv);
      *(bf16x4*)(Ob + qrow + df * 16 + lh * 4) = ov;
    }
  }
}

extern "C" void kernel_launch(void* const* d_in, const int* in_sizes, int n_in,
                              void* d_out, int out_size, void* d_ws, size_t ws_size,
                              hipStream_t stream) {
  const float* x     = (const float*)d_in[0];
  const float* ctx   = (const float*)d_in[1];
  const float* Wq    = (const float*)d_in[2];
  const float* Wkv   = (const float*)d_in[3];
  const float* Wproj = (const float*)d_in[4];
  const float* qg    = (const float*)d_in[5];
  const float* kg    = (const float*)d_in[6];
  float* out = (float*)d_out;

  // B=4 L=4096 Lc=1024 D=1024 CTX=1024 H=16 hd=64
  char* ws = (char*)d_ws;
  __bf16* xb   = (__bf16*)(ws);                        // 32MB [16384,1024]; reused as Ob
  __bf16* cb   = (__bf16*)(ws + (size_t)32 * 1048576); // 8MB  [4096,1024]
  __bf16* Wqt  = (__bf16*)(ws + (size_t)40 * 1048576); // 2MB
  __bf16* Wkvt = (__bf16*)(ws + (size_t)42 * 1048576); // 4MB
  __bf16* Wpt  = (__bf16*)(ws + (size_t)46 * 1048576); // 2MB
  __bf16* Qb   = (__bf16*)(ws + (size_t)48 * 1048576); // 32MB
  __bf16* Kb   = (__bf16*)(ws + (size_t)80 * 1048576); // 8MB  [4096,1024]
  __bf16* Vt   = (__bf16*)(ws + (size_t)88 * 1048576); // 8MB  [b,h,d,kvp]
  __bf16* Ob   = xb;  // xb is dead after the Q GEMM

  conv_bf16_kernel<<<16384, 256, 0, stream>>>(x, xb, 4194304);
  conv_bf16_kernel<<<4096, 256, 0, stream>>>(ctx, cb, 1048576);
  tconv_kernel<<<dim3(32, 32), dim3(32, 8), 0, stream>>>(Wq, Wqt, 1024, 1024);
  tconv_kernel<<<dim3(64, 32), dim3(32, 8), 0, stream>>>(Wkv, Wkvt, 1024, 2048);
  tconv_kernel<<<dim3(32, 32), dim3(32, 8), 0, stream>>>(Wproj, Wpt, 1024, 1024);

  // Q = xb Wq (+q RMSNorm fused, softmax scale folded), bf16 A via gl_lds
  gemm_kernel<1, 0><<<dim3(8, 128), 256, 0, stream>>>(xb, Wqt, Qb, nullptr, 16384, 1024, 1024, qg);
  // KV = cb Wkv (+k RMSNorm on K half; V transposed+permuted), bf16 A via gl_lds
  gemm_kernel<2, 0><<<dim3(16, 32), 256, 0, stream>>>(cb, Wkvt, Kb, Vt, 4096, 2048, 1024, kg);
  flash_kernel<<<1024, 512, 0, stream>>>(Qb, Kb, Vt, Ob);
  // out = O Wproj, f32 out
  gemm_kernel<0, 1><<<dim3(8, 128), 256, 0, stream>>>(Ob, Wpt, out, nullptr, 16384, 1024, 1024, nullptr);
}

// Round 24
// 232.780 us; speedup vs baseline: 1.3564x; 1.0349x over previous
//
#include <hip/hip_runtime.h>

typedef __bf16 bf16x8 __attribute__((ext_vector_type(8)));
typedef __bf16 bf16x4 __attribute__((ext_vector_type(4)));
typedef float f32x4 __attribute__((ext_vector_type(4)));

__device__ __forceinline__ void gl_lds16(const void* g, void* l) {
  __builtin_amdgcn_global_load_lds(
      (const __attribute__((address_space(1))) unsigned int*)g,
      (__attribute__((address_space(3))) unsigned int*)l, 16, 0, 0);
}

// ---------------- fused f32 -> bf16 convert: x (4194304 f32x4) then ctx (1048576) ------
__global__ __launch_bounds__(256) void conv2_bf16_kernel(
    const float* __restrict__ x, __bf16* __restrict__ xb,
    const float* __restrict__ ctx, __bf16* __restrict__ cb) {
  int i = blockIdx.x * 256 + threadIdx.x;
  const float* in;
  __bf16* out;
  if (i < 4194304) { in = x; out = xb; }
  else             { in = ctx; out = cb; i -= 4194304; }
  float4 v = ((const float4*)in)[i];
  bf16x4 o;
  o[0] = (__bf16)v.x; o[1] = (__bf16)v.y; o[2] = (__bf16)v.z; o[3] = (__bf16)v.w;
  *(bf16x4*)(out + (size_t)i * 4) = o;
}

// ---------------- fused weight transposes: f32 [R][C] -> bf16 [C][R], 3 weights --------
// z=0: Wq [1024,1024]; z=1: Wproj [1024,1024]; z=2,3: Wkv [1024,2048] column halves.
__global__ __launch_bounds__(256) void tconv3_kernel(
    const float* __restrict__ Wq, const float* __restrict__ Wkv,
    const float* __restrict__ Wproj, __bf16* __restrict__ Wqt,
    __bf16* __restrict__ Wkvt, __bf16* __restrict__ Wpt) {
  __shared__ float t[32][33];
  const int z = blockIdx.z;
  const float* W;
  __bf16* Wt;
  int C, c0;
  const int R = 1024;
  if (z == 0)      { W = Wq;    Wt = Wqt;  C = 1024; c0 = blockIdx.x * 32; }
  else if (z == 1) { W = Wproj; Wt = Wpt;  C = 1024; c0 = blockIdx.x * 32; }
  else             { W = Wkv;   Wt = Wkvt; C = 2048; c0 = (blockIdx.x + (z - 2) * 32) * 32; }
  const int r0 = blockIdx.y * 32;
  const int tx = threadIdx.x, ty = threadIdx.y;
#pragma unroll
  for (int i = 0; i < 4; ++i)
    t[ty + i * 8][tx] = W[(size_t)(r0 + ty + i * 8) * C + c0 + tx];
  __syncthreads();
#pragma unroll
  for (int i = 0; i < 4; ++i)
    Wt[(size_t)(c0 + ty + i * 8) * R + r0 + tx] = (__bf16)t[tx][ty + i * 8];
}

// ---------------- bf16 GEMM (2-phase dbuf, gl_lds A+B): C[M,N] = A[M,K] * Bt[N,K]^T ----
// NORM==1: per-64-col RMSNorm (q) with the softmax scale C=log2(e)/8 folded in.
// NORM==2: KV mode (K compact + V transp-permute). NORM==0: plain; OUTF32 -> f32 out.
template <int NORM, int OUTF32>
__global__ __launch_bounds__(256) void gemm_kernel(
    const __bf16* __restrict__ Ab, const __bf16* __restrict__ Bt,
    void* __restrict__ Cout, void* __restrict__ Cout2,
    int M, int N, int K, const float* __restrict__ gamma) {
  __shared__ alignas(16) __bf16 Alds[2][128 * 32];
  __shared__ alignas(16) __bf16 Blds[2][128 * 32];
  const int tid = threadIdx.x;
  const int w = tid >> 6, l = tid & 63;
  const int lg = l & 15, lh = l >> 4;
  const int wr = w >> 1, wc = w & 1;

  // XCD-bijective swizzle: same-XCD blocks walk bcol fastest within a brow-slab.
  const int nbx = gridDim.x;
  const int lid = blockIdx.y * nbx + blockIdx.x;
  const int cpx = (nbx * gridDim.y) >> 3;
  const int swz = (lid & 7) * cpx + (lid >> 3);
  const int brow = (swz / nbx) * 128, bcol = (swz % nbx) * 128;

  const f32x4 zero = {0.f, 0.f, 0.f, 0.f};
  f32x4 acc[4][4];
#pragma unroll
  for (int m = 0; m < 4; ++m)
#pragma unroll
    for (int n = 0; n < 4; ++n) acc[m][n] = zero;

  auto STAGE = [&](int buf, int k0) {
#pragma unroll
    for (int j = 0; j < 2; ++j) {
      int c = j * 256 + w * 64 + l;
      gl_lds16(Ab + (size_t)(brow + (c >> 2)) * K + k0 + (c & 3) * 8,
               (char*)Alds[buf] + (j * 256 + w * 64) * 16);
      gl_lds16(Bt + (size_t)(bcol + (c >> 2)) * K + k0 + (c & 3) * 8,
               (char*)Blds[buf] + (j * 256 + w * 64) * 16);
    }
  };

  STAGE(0, 0);
  __syncthreads();
  for (int k0 = 0; k0 < K; k0 += 32) {
    int cur = (k0 >> 5) & 1;
    if (k0 + 32 < K) STAGE(cur ^ 1, k0 + 32);
    bf16x8 af[4], bfr[4];
#pragma unroll
    for (int m = 0; m < 4; ++m)
      af[m] = *(const bf16x8*)(Alds[cur] + (wr * 64 + m * 16 + lg) * 32 + lh * 8);
#pragma unroll
    for (int n = 0; n < 4; ++n)
      bfr[n] = *(const bf16x8*)(Blds[cur] + (wc * 64 + n * 16 + lg) * 32 + lh * 8);
#pragma unroll
    for (int m = 0; m < 4; ++m)
#pragma unroll
      for (int n = 0; n < 4; ++n)
        acc[m][n] = __builtin_amdgcn_mfma_f32_16x16x32_bf16(af[m], bfr[n], acc[m][n], 0, 0, 0);
    __syncthreads();
  }

  const int col64 = bcol + wc * 64;
  if (NORM == 1 || (NORM == 2 && col64 < 1024)) {
    const float QS = (NORM == 1) ? 0.18033688f : 1.0f;  // fold log2(e)/8 into Q
    float gm[4];
#pragma unroll
    for (int n = 0; n < 4; ++n) gm[n] = gamma[n * 16 + lg] * QS;
#pragma unroll
    for (int m = 0; m < 4; ++m) {
#pragma unroll
      for (int i = 0; i < 4; ++i) {
        float ss = 0.f;
#pragma unroll
        for (int n = 0; n < 4; ++n) ss += acc[m][n][i] * acc[m][n][i];
        ss += __shfl_xor(ss, 1);
        ss += __shfl_xor(ss, 2);
        ss += __shfl_xor(ss, 4);
        ss += __shfl_xor(ss, 8);
        float inv = rsqrtf(ss * (1.0f / 64.0f) + 1e-6f);
#pragma unroll
        for (int n = 0; n < 4; ++n) acc[m][n][i] *= inv * gm[n];
      }
    }
  }

  if (NORM == 2) {
    if (col64 < 1024) {
#pragma unroll
      for (int m = 0; m < 4; ++m)
#pragma unroll
        for (int n = 0; n < 4; ++n)
#pragma unroll
          for (int i = 0; i < 4; ++i) {
            size_t idx = (size_t)(brow + wr * 64 + m * 16 + lh * 4 + i) * 1024 +
                         col64 + n * 16 + lg;
            ((__bf16*)Cout)[idx] = (__bf16)acc[m][n][i];
          }
    } else {
      // V half -> Vt[b,h,d,kvp]: i-dim = 4 consecutive kv = contiguous after permute
#pragma unroll
      for (int m = 0; m < 4; ++m) {
        int row = brow + wr * 64 + m * 16 + lh * 4;   // global ctx row = b*1024 + kv
        int bb = row >> 10, kv0 = row & 1023;
        int g = kv0 & 31;
        int pos = (kv0 & ~31) + ((g & 15) >> 2) * 8 + (g >> 4) * 4;
#pragma unroll
        for (int n = 0; n < 4; ++n) {
          int col = col64 + n * 16 + lg - 1024;       // = h*64 + d
          bf16x4 v;
#pragma unroll
          for (int i = 0; i < 4; ++i) v[i] = (__bf16)acc[m][n][i];
          *(bf16x4*)((__bf16*)Cout2 + ((size_t)(bb * 1024 + col)) * 1024 + pos) = v;
        }
      }
    }
    return;
  }

#pragma unroll
  for (int m = 0; m < 4; ++m)
#pragma unroll
    for (int n = 0; n < 4; ++n)
#pragma unroll
      for (int i = 0; i < 4; ++i) {
        size_t idx = (size_t)(brow + wr * 64 + m * 16 + lh * 4 + i) * N +
                     bcol + wc * 64 + n * 16 + lg;
        if (OUTF32) ((float*)Cout)[idx] = acc[m][n][i];
        else ((__bf16*)Cout)[idx] = (__bf16)acc[m][n][i];
      }
}

// ---------------- flash attention v12: pre-scaled Q, shift-free softmax ----------------
// Q was pre-scaled by C=log2(e)/8 in the Q-GEMM epilogue, so st = S*C and
// P = exp2(st) directly. |st| <= 64*C = 11.54 -> P <= 2^11.54 ~ 2900 (f32/bf16 safe);
// the softmax shift cancels between numerator and denominator (O = sum(PV)/sum(P)).
__global__ __launch_bounds__(512) void flash_kernel(
    const __bf16* __restrict__ Qb, const __bf16* __restrict__ Kb,
    const __bf16* __restrict__ Vt, __bf16* __restrict__ Ob) {
  // XCD-aware bijective swizzle: 1024 blocks, 8 XCDs, 128 per XCD.
  const int orig = blockIdx.x;
  const int wgid = (orig & 7) * 128 + (orig >> 3);
  const int qt = wgid & 15, h = (wgid >> 4) & 15, b = wgid >> 8;
  const int tid = threadIdx.x;
  const int w = tid >> 6, l = tid & 63, lg = l & 15, lh = l >> 4;
  // K buf n at n*8192 ; V buf n at 32768 + n*8192  (n = 0..3)
  __shared__ alignas(16) char lds[65536];

  const int qrow0 = b * 4096 + qt * 256 + w * 32;
  bf16x8 qfr[2][2];
#pragma unroll
  for (int mff = 0; mff < 2; ++mff)
#pragma unroll
    for (int dc = 0; dc < 2; ++dc)
      qfr[mff][dc] = *(const bf16x8*)(Qb + (size_t)(qrow0 + mff * 16 + lg) * 1024 +
                                      h * 64 + dc * 32 + lh * 8);

  const char* Kg = (const char*)Kb + (size_t)b * 2097152 + h * 128;  // row stride 2048B
  const char* Vg = (const char*)Vt + (size_t)(b * 16 + h) * 64 * 2048;

  // staging: per-thread 1 K-load + 1 V-load per tile; linear LDS dest, pre-swizzled src
  const int o16 = tid * 16;
  const int op = o16 ^ (((o16 >> 7) & 7) << 4);
  const int srow = op >> 7, scb = op & 127;

  auto STAGE = [&](int buf, int kt) {
    gl_lds16(Kg + (size_t)(kt * 64 + srow) * 2048 + scb, lds + buf * 8192 + w * 1024);
    gl_lds16(Vg + (size_t)srow * 2048 + kt * 128 + scb, lds + 32768 + buf * 8192 + w * 1024);
  };

  // hoisted lane-invariant LDS read offsets
  const int swzl = (lg & 7) << 4;
  const int off0 = lg * 128 + ((lh * 16) ^ swzl);
  const int off1 = lg * 128 + ((64 + lh * 16) ^ swzl);

  const f32x4 zero = {0.f, 0.f, 0.f, 0.f};
  f32x4 o_[4][2];   // [df][qf] : O^T frag, row d = df*16+lh*4+i, col q = qf*16+lg
  float lp_[2];
#pragma unroll
  for (int df = 0; df < 4; ++df)
#pragma unroll
    for (int qf = 0; qf < 2; ++qf) o_[df][qf] = zero;
  lp_[0] = lp_[1] = 0.f;

  auto COMPUTE = [&](const char* Kc, const char* Vc) {
    // S^T[kv][q] : A = K rows (kv), B = Q cols (q); first K-slice uses zero C
    f32x4 st[4][2];
    __builtin_amdgcn_s_setprio(1);
#pragma unroll
    for (int kvf = 0; kvf < 4; ++kvf) {
      bf16x8 kf = *(const bf16x8*)(Kc + off0 + kvf * 2048);
#pragma unroll
      for (int mff = 0; mff < 2; ++mff)
        st[kvf][mff] = __builtin_amdgcn_mfma_f32_16x16x32_bf16(kf, qfr[mff][0], zero, 0, 0, 0);
    }
#pragma unroll
    for (int kvf = 0; kvf < 4; ++kvf) {
      bf16x8 kf = *(const bf16x8*)(Kc + off1 + kvf * 2048);
#pragma unroll
      for (int mff = 0; mff < 2; ++mff)
        st[kvf][mff] = __builtin_amdgcn_mfma_f32_16x16x32_bf16(kf, qfr[mff][1], st[kvf][mff], 0, 0, 0);
    }
    __builtin_amdgcn_s_setprio(0);

    // P = exp2(st) (Q pre-scaled; shift cancels), per-lane partial row-sum, direct pack
    bf16x8 pw[2][2];
#pragma unroll
    for (int qf = 0; qf < 2; ++qf) {
      float rs = 0.f;
#pragma unroll
      for (int kvf = 0; kvf < 4; ++kvf) {
#pragma unroll
        for (int i = 0; i < 4; ++i) {
          float p = __builtin_amdgcn_exp2f(st[kvf][qf][i]);
          pw[kvf >> 1][qf][(kvf & 1) * 4 + i] = (__bf16)p;
          rs += p;
        }
      }
      lp_[qf] += rs;   // cross-lane reduce deferred to epilogue
    }

    // O^T += V^T P : K32 MFMA; b128 V read = A-frag, pw = B-frag
    __builtin_amdgcn_s_setprio(1);
#pragma unroll
    for (int p = 0; p < 2; ++p)
#pragma unroll
      for (int df = 0; df < 4; ++df) {
        bf16x8 vv = *(const bf16x8*)(Vc + (p ? off1 : off0) + df * 2048);
#pragma unroll
        for (int qf = 0; qf < 2; ++qf)
          o_[df][qf] = __builtin_amdgcn_mfma_f32_16x16x32_bf16(vv, pw[p][qf], o_[df][qf], 0, 0, 0);
      }
    __builtin_amdgcn_s_setprio(0);
  };

  STAGE(0, 0);
  STAGE(1, 1);
  __syncthreads();
#pragma unroll 2
  for (int it = 0; it < 8; ++it) {
    const int pb_ = (it & 1) * 2;           // current buffer pair {pb_, pb_+1}
    if (it < 7) {                           // prefetch next pair (read-done via prev barrier)
      STAGE(pb_ ^ 2, 2 * it + 2);
      STAGE((pb_ ^ 2) + 1, 2 * it + 3);
    }
    COMPUTE(lds + pb_ * 8192, lds + 32768 + pb_ * 8192);
    COMPUTE(lds + (pb_ + 1) * 8192, lds + 32768 + (pb_ + 1) * 8192);
    // drain this iteration's prefetch before the single barrier per 2 tiles
    asm volatile("s_waitcnt vmcnt(0)" ::: "memory");
    __syncthreads();
  }

  // final l reduce + normalize + store (i-dim = consecutive d -> 8B stores)
#pragma unroll
  for (int qf = 0; qf < 2; ++qf) {
    float ls = lp_[qf];
    ls += __shfl_xor(ls, 16);
    ls += __shfl_xor(ls, 32);
    float inv = 1.f / ls;
    size_t qrow = (size_t)(qrow0 + qf * 16 + lg) * 1024 + h * 64;
#pragma unroll
    for (int df = 0; df < 4; ++df) {
      bf16x4 ov;
#pragma unroll
      for (int i = 0; i < 4; ++i) ov[i] = (__bf16)(o_[df][qf][i] * inv);
      *(bf16x4*)(Ob + qrow + df * 16 + lh * 4) = ov;
    }
  }
}

extern "C" void kernel_launch(void* const* d_in, const int* in_sizes, int n_in,
                              void* d_out, int out_size, void* d_ws, size_t ws_size,
                              hipStream_t stream) {
  const float* x     = (const float*)d_in[0];
  const float* ctx   = (const float*)d_in[1];
  const float* Wq    = (const float*)d_in[2];
  const float* Wkv   = (const float*)d_in[3];
  const float* Wproj = (const float*)d_in[4];
  const float* qg    = (const float*)d_in[5];
  const float* kg    = (const float*)d_in[6];
  float* out = (float*)d_out;

  // B=4 L=4096 Lc=1024 D=1024 CTX=1024 H=16 hd=64
  char* ws = (char*)d_ws;
  __bf16* xb   = (__bf16*)(ws);                        // 32MB [16384,1024]; reused as Ob
  __bf16* cb   = (__bf16*)(ws + (size_t)32 * 1048576); // 8MB  [4096,1024]
  __bf16* Wqt  = (__bf16*)(ws + (size_t)40 * 1048576); // 2MB
  __bf16* Wkvt = (__bf16*)(ws + (size_t)42 * 1048576); // 4MB
  __bf16* Wpt  = (__bf16*)(ws + (size_t)46 * 1048576); // 2MB
  __bf16* Qb   = (__bf16*)(ws + (size_t)48 * 1048576); // 32MB
  __bf16* Kb   = (__bf16*)(ws + (size_t)80 * 1048576); // 8MB  [4096,1024]
  __bf16* Vt   = (__bf16*)(ws + (size_t)88 * 1048576); // 8MB  [b,h,d,kvp]
  __bf16* Ob   = xb;  // xb is dead after the Q GEMM

  // fused prologue: both input converts in one launch; all 3 weight transposes in one
  conv2_bf16_kernel<<<20480, 256, 0, stream>>>(x, xb, ctx, cb);
  tconv3_kernel<<<dim3(32, 32, 4), dim3(32, 8), 0, stream>>>(Wq, Wkv, Wproj, Wqt, Wkvt, Wpt);

  // Q = xb Wq (+q RMSNorm fused, softmax scale folded), bf16 A via gl_lds
  gemm_kernel<1, 0><<<dim3(8, 128), 256, 0, stream>>>(xb, Wqt, Qb, nullptr, 16384, 1024, 1024, qg);
  // KV = cb Wkv (+k RMSNorm on K half; V transposed+permuted), bf16 A via gl_lds
  gemm_kernel<2, 0><<<dim3(16, 32), 256, 0, stream>>>(cb, Wkvt, Kb, Vt, 4096, 2048, 1024, kg);
  flash_kernel<<<1024, 512, 0, stream>>>(Qb, Kb, Vt, Ob);
  // out = O Wproj, f32 out
  gemm_kernel<0, 1><<<dim3(8, 128), 256, 0, stream>>>(Ob, Wpt, out, nullptr, 16384, 1024, 1024, nullptr);
}